// Round 2
// baseline (767.894 us; speedup 1.0000x reference)
//
#include <hip/hip_runtime.h>

typedef short bf16x8 __attribute__((ext_vector_type(8)));
typedef float f32x4 __attribute__((ext_vector_type(4)));
typedef unsigned short u16;

#define S_LEN 4096
#define D_DIM 256
#define NROW  16384   // B*S

__device__ __forceinline__ u16 f2bf(float f) {
    union { float f; unsigned u; } v; v.f = f;
    unsigned r = v.u + 0x7FFFu + ((v.u >> 16) & 1u);
    return (u16)(r >> 16);
}

// ---------------- Kernel W: convert Wq/Wk/Wv f32 -> bf16 ------------------
__global__ __launch_bounds__(256) void wconv(
    const float* __restrict__ Wq, const float* __restrict__ Wk,
    const float* __restrict__ Wv, u16* __restrict__ Wb)
{
    int i = blockIdx.x * 256 + threadIdx.x;   // 24576 threads, 8 elems each
    int m = i >> 13;                          // 8192 threads per 64K matrix
    int off = (i & 8191) * 8;
    const float* s = (m == 0 ? Wq : (m == 1 ? Wk : Wv)) + off;
    float4 v0 = *reinterpret_cast<const float4*>(s);
    float4 v1 = *reinterpret_cast<const float4*>(s + 4);
    union { ushort4 h[2]; int4 q; } t;
    t.h[0] = make_ushort4(f2bf(v0.x), f2bf(v0.y), f2bf(v0.z), f2bf(v0.w));
    t.h[1] = make_ushort4(f2bf(v1.x), f2bf(v1.y), f2bf(v1.z), f2bf(v1.w));
    *reinterpret_cast<int4*>(Wb + m * 65536 + off) = t.q;
}

// ---------------- Kernel A: QKV projection (16 rows/block) ----------------
// Writes Qb, Kb row-major bf16 [16384][256]; V transposed into 64-key
// panels: Vt[((b*64+kt)*256 + d)*64 + (s%64)]
__global__ __launch_bounds__(256) void qkv_proj(
    const float* __restrict__ x, const u16* __restrict__ Wb,
    const float* __restrict__ bq, const float* __restrict__ bk,
    const float* __restrict__ bv,
    u16* __restrict__ Qb, u16* __restrict__ Kb, u16* __restrict__ Vt)
{
    __shared__ u16 xs[16][264];
    const int tid = threadIdx.x;
    const int r0 = blockIdx.x * 16;

    #pragma unroll
    for (int i = 0; i < 4; ++i) {
        int c = i * 256 + tid;               // 1024 float4 chunks
        int row = c >> 6, c4 = c & 63;
        float4 v = reinterpret_cast<const float4*>(x + (size_t)(r0 + row) * D_DIM)[c4];
        *reinterpret_cast<ushort4*>(&xs[row][c4 * 4]) =
            make_ushort4(f2bf(v.x), f2bf(v.y), f2bf(v.z), f2bf(v.w));
    }
    __syncthreads();

    const int w = tid >> 6, l = tid & 63, lr = l & 15, lg = l >> 4;
    const int c0 = w * 64;

    bf16x8 a[8];
    #pragma unroll
    for (int kk = 0; kk < 8; ++kk)
        a[kk] = *reinterpret_cast<const bf16x8*>(&xs[lr][kk * 32 + lg * 8]);

    const float* Bs[3] = {bq, bk, bv};

    #pragma unroll
    for (int m = 0; m < 3; ++m) {
        const u16* Wm = Wb + m * 65536;
        f32x4 acc[4] = {};
        #pragma unroll
        for (int kk = 0; kk < 8; ++kk) {
            #pragma unroll
            for (int cf = 0; cf < 4; ++cf) {
                bf16x8 wf = *reinterpret_cast<const bf16x8*>(
                    &Wm[(size_t)(c0 + cf * 16 + lr) * D_DIM + kk * 32 + lg * 8]);
                acc[cf] = __builtin_amdgcn_mfma_f32_16x16x32_bf16(a[kk], wf, acc[cf], 0, 0, 0);
            }
        }
        #pragma unroll
        for (int cf = 0; cf < 4; ++cf) {
            float bias = Bs[m][c0 + cf * 16 + lr];
            if (m < 2) {
                u16* outp = (m == 0) ? Qb : Kb;
                #pragma unroll
                for (int r = 0; r < 4; ++r)
                    outp[(size_t)(r0 + lg * 4 + r) * D_DIM + c0 + cf * 16 + lr] =
                        f2bf(acc[cf][r] + bias);
            } else {
                int d  = c0 + cf * 16 + lr;
                int bi = r0 >> 12;
                int kt = (r0 & 4095) >> 6;
                int sl = (r0 & 63) + lg * 4;
                ushort4 h = make_ushort4(
                    f2bf(acc[cf][0] + bias), f2bf(acc[cf][1] + bias),
                    f2bf(acc[cf][2] + bias), f2bf(acc[cf][3] + bias));
                *reinterpret_cast<ushort4*>(
                    &Vt[((size_t)((bi * 64 + kt) * 256 + d)) * 64 + sl]) = h;
            }
        }
    }
}

// ---------------- Kernel B: column softmax log-denominators ---------------
// LZ[b,k] = ln( sum_q exp(s[b,q,k]/16) ).  Block = 16 keys x 4 q-quarters.
__global__ __launch_bounds__(256) void col_denom(
    const u16* __restrict__ Qb, const u16* __restrict__ Kb, float* __restrict__ LZ)
{
    __shared__ float zbuf[4][16];
    const int tid = threadIdx.x, blk = blockIdx.x;
    const int w = tid >> 6, l = tid & 63, lr = l & 15, lg = l >> 4;
    const int b  = (blk & 7) >> 1;                  // XCD-cluster batches
    const int k0 = (((blk >> 3) << 1) | (blk & 1)) * 16;

    bf16x8 kreg[8];
    #pragma unroll
    for (int kk = 0; kk < 8; ++kk)
        kreg[kk] = *reinterpret_cast<const bf16x8*>(
            &Kb[((size_t)(b * S_LEN + k0 + lr)) * D_DIM + kk * 32 + lg * 8]);

    float Z[4] = {0.f, 0.f, 0.f, 0.f};
    const float SC = 0.0625f;

    for (int qt = 0; qt < 16; ++qt) {
        const int q0 = (w * 16 + qt) * 64;
        f32x4 acc[4] = {};
        #pragma unroll
        for (int kk = 0; kk < 8; ++kk) {
            #pragma unroll
            for (int cf = 0; cf < 4; ++cf) {
                bf16x8 qf = *reinterpret_cast<const bf16x8*>(
                    &Qb[((size_t)(b * S_LEN + q0 + cf * 16 + lr)) * D_DIM + kk * 32 + lg * 8]);
                acc[cf] = __builtin_amdgcn_mfma_f32_16x16x32_bf16(kreg[kk], qf, acc[cf], 0, 0, 0);
            }
        }
        #pragma unroll
        for (int cf = 0; cf < 4; ++cf)
            #pragma unroll
            for (int r = 0; r < 4; ++r)
                Z[r] += __expf(acc[cf][r] * SC);
    }
    #pragma unroll
    for (int r = 0; r < 4; ++r) {
        float z = Z[r];
        z += __shfl_xor(z, 1);
        z += __shfl_xor(z, 2);
        z += __shfl_xor(z, 4);
        z += __shfl_xor(z, 8);
        if (lr == 0) zbuf[w][lg * 4 + r] = z;
    }
    __syncthreads();
    if (tid < 16)
        LZ[b * S_LEN + k0 + tid] =
            logf(zbuf[0][tid] + zbuf[1][tid] + zbuf[2][tid] + zbuf[3][tid]);
}

// ---------------- Kernel C: out = (exp(S)/Z) @ V --------------------------
// Block = one 16-query tile x 4 key-quarters (one per wave). Waves run
// barrier-free: K/V fragments straight from L2, P transposed via a tiny
// per-wave LDS slice. Final cross-wave oacc reduction reuses LDS.
__global__ __launch_bounds__(256, 4) void attn_out(
    const u16* __restrict__ Qb, const u16* __restrict__ Kb, const u16* __restrict__ Vt,
    const float* __restrict__ LZ, float* __restrict__ out)
{
    __shared__ __align__(16) char smem[32768];
    const int tid = threadIdx.x, blk = blockIdx.x;
    const int b  = (blk & 7) >> 1;                  // XCD-cluster batches
    const int qs = ((blk >> 3) << 1) | (blk & 1);   // 0..255 q16-tile
    const int w = tid >> 6, l = tid & 63, lr = l & 15, lg = l >> 4;
    const int q0 = qs * 16;

    u16* ps = reinterpret_cast<u16*>(smem) + w * 1152;   // [16][72] per wave

    bf16x8 qreg[8];
    #pragma unroll
    for (int kk = 0; kk < 8; ++kk)
        qreg[kk] = *reinterpret_cast<const bf16x8*>(
            &Qb[((size_t)(b * S_LEN + q0 + lr)) * D_DIM + kk * 32 + lg * 8]);

    f32x4 oacc[16] = {};
    const float SC = 0.0625f;

    for (int kt = w * 16; kt < w * 16 + 16; ++kt) {
        const int kbase = kt * 64;
        f32x4 sacc[4] = {};
        #pragma unroll
        for (int kk = 0; kk < 8; ++kk) {
            #pragma unroll
            for (int cf = 0; cf < 4; ++cf) {
                bf16x8 kf = *reinterpret_cast<const bf16x8*>(
                    &Kb[((size_t)(b * S_LEN + kbase + cf * 16 + lr)) * D_DIM + kk * 32 + lg * 8]);
                sacc[cf] = __builtin_amdgcn_mfma_f32_16x16x32_bf16(qreg[kk], kf, sacc[cf], 0, 0, 0);
            }
        }
        #pragma unroll
        for (int cf = 0; cf < 4; ++cf) {
            float L = LZ[b * S_LEN + kbase + cf * 16 + lr];
            #pragma unroll
            for (int r = 0; r < 4; ++r) {
                float p = __expf(fmaf(sacc[cf][r], SC, -L));
                ps[(lg * 4 + r) * 72 + cf * 16 + lr] = f2bf(p);
            }
        }
        #pragma unroll
        for (int kk2 = 0; kk2 < 2; ++kk2) {
            bf16x8 af = *reinterpret_cast<const bf16x8*>(&ps[lr * 72 + kk2 * 32 + lg * 8]);
            #pragma unroll
            for (int cf2 = 0; cf2 < 16; ++cf2) {
                int d = cf2 * 16 + lr;
                bf16x8 vf = *reinterpret_cast<const bf16x8*>(
                    &Vt[((size_t)(b * 64 + kt) * 256 + d) * 64 + kk2 * 32 + lg * 8]);
                oacc[cf2] = __builtin_amdgcn_mfma_f32_16x16x32_bf16(af, vf, oacc[cf2], 0, 0, 0);
            }
        }
    }

    // ---- cross-wave reduction of oacc (reuse smem) ----
    float* red = reinterpret_cast<float*>(smem);     // 2 x 4096 f32
    __syncthreads();
    if (w == 1) {
        #pragma unroll
        for (int c = 0; c < 16; ++c)
            *reinterpret_cast<f32x4*>(&red[c * 256 + l * 4]) = oacc[c];
    }
    if (w == 3) {
        #pragma unroll
        for (int c = 0; c < 16; ++c)
            *reinterpret_cast<f32x4*>(&red[4096 + c * 256 + l * 4]) = oacc[c];
    }
    __syncthreads();
    if (w == 0) {
        #pragma unroll
        for (int c = 0; c < 16; ++c)
            oacc[c] += *reinterpret_cast<f32x4*>(&red[c * 256 + l * 4]);
    }
    if (w == 2) {
        #pragma unroll
        for (int c = 0; c < 16; ++c)
            oacc[c] += *reinterpret_cast<f32x4*>(&red[4096 + c * 256 + l * 4]);
    }
    __syncthreads();
    if (w == 2) {
        #pragma unroll
        for (int c = 0; c < 16; ++c)
            *reinterpret_cast<f32x4*>(&red[c * 256 + l * 4]) = oacc[c];
    }
    __syncthreads();
    if (w == 0) {
        #pragma unroll
        for (int c = 0; c < 16; ++c)
            oacc[c] += *reinterpret_cast<f32x4*>(&red[c * 256 + l * 4]);
        #pragma unroll
        for (int c = 0; c < 16; ++c) {
            #pragma unroll
            for (int r = 0; r < 4; ++r) {
                int row = q0 + lg * 4 + r;
                out[((size_t)(b * S_LEN + row)) * D_DIM + c * 16 + lr] = oacc[c][r];
            }
        }
    }
}

// ---------------- launcher ------------------------------------------------
extern "C" void kernel_launch(void* const* d_in, const int* in_sizes, int n_in,
                              void* d_out, int out_size, void* d_ws, size_t ws_size,
                              hipStream_t stream) {
    const float* x  = (const float*)d_in[0];
    const float* Wq = (const float*)d_in[1];
    const float* bq = (const float*)d_in[2];
    const float* Wk = (const float*)d_in[3];
    const float* bk = (const float*)d_in[4];
    const float* Wv = (const float*)d_in[5];
    const float* bv = (const float*)d_in[6];
    float* out = (float*)d_out;

    u16* Qb = (u16*)d_ws;                            // 8 MB
    u16* Kb = Qb + (size_t)NROW * D_DIM;             // 8 MB
    u16* Vt = Kb + (size_t)NROW * D_DIM;             // 8 MB
    float* LZ = (float*)(Vt + (size_t)NROW * D_DIM); // 64 KB
    u16* Wb = (u16*)(LZ + NROW);                     // 384 KB

    wconv<<<96, 256, 0, stream>>>(Wq, Wk, Wv, Wb);
    qkv_proj<<<NROW / 16, 256, 0, stream>>>(x, Wb, bq, bk, bv, Qb, Kb, Vt);
    col_denom<<<1024, 256, 0, stream>>>(Qb, Kb, LZ);
    attn_out<<<1024, 256, 0, stream>>>(Qb, Kb, Vt, LZ, out);
}

// Round 3
// 362.348 us; speedup vs baseline: 2.1192x; 2.1192x over previous
//
#include <hip/hip_runtime.h>

typedef short bf16x8 __attribute__((ext_vector_type(8)));
typedef float f32x4 __attribute__((ext_vector_type(4)));
typedef unsigned short u16;

#define S_LEN 4096
#define D_DIM 256
#define NROW  16384   // B*S

__device__ __forceinline__ u16 f2bf(float f) {
    union { float f; unsigned u; } v; v.f = f;
    unsigned r = v.u + 0x7FFFu + ((v.u >> 16) & 1u);
    return (u16)(r >> 16);
}

// Fragment-linear layouts (bf16):
//  Q/K/W: row-tile t (16 rows), kk (32-k chunk): frag = t*4096 + kk*512,
//         elem(row_local, col) at ((col>>3)&3)*128 + row_local*8 + (col&7).
//         Lane l reads frag + l*8 -> row=l&15, k=(l>>4)*8+e. 1KB coalesced.
//  V^T:   panel p = b*64+kt (64 keys x 256 d = 32KB): frag(dtile,kk2) =
//         p*16384 + (dtile*2+kk2)*512, elem(d_local, key) likewise.
__device__ __forceinline__ size_t fr_qk(int t, int kk) {
    return (size_t)t * 4096 + kk * 512;
}
__device__ __forceinline__ size_t fr_v(int p, int dt, int kk2) {
    return (size_t)p * 16384 + (dt * 2 + kk2) * 512;
}

// ---------------- Kernel W: W f32 -> bf16 fragments -----------------------
__global__ __launch_bounds__(256) void wconv(
    const float* __restrict__ Wq, const float* __restrict__ Wk,
    const float* __restrict__ Wv, u16* __restrict__ Wf)
{
    int i = blockIdx.x * 256 + threadIdx.x;   // 24576 threads
    int m = i >> 13;
    int idx = i & 8191;
    int ocol = idx >> 5;                      // 0..255 (row of W = out col)
    int d0 = (idx & 31) * 8;
    const float* s = (m == 0 ? Wq : (m == 1 ? Wk : Wv)) + ocol * 256 + d0;
    float4 v0 = *reinterpret_cast<const float4*>(s);
    float4 v1 = *reinterpret_cast<const float4*>(s + 4);
    union { ushort4 h[2]; int4 q; } t;
    t.h[0] = make_ushort4(f2bf(v0.x), f2bf(v0.y), f2bf(v0.z), f2bf(v0.w));
    t.h[1] = make_ushort4(f2bf(v1.x), f2bf(v1.y), f2bf(v1.z), f2bf(v1.w));
    size_t off = (size_t)m * 65536 + fr_qk(ocol >> 4, d0 >> 5)
               + ((d0 >> 3) & 3) * 128 + (ocol & 15) * 8;
    *reinterpret_cast<int4*>(Wf + off) = t.q;
}

// ---------------- Kernel A: QKV projection (16 rows/block) ----------------
__global__ __launch_bounds__(256) void qkv_proj(
    const float* __restrict__ x, const u16* __restrict__ Wf,
    const float* __restrict__ bq, const float* __restrict__ bk,
    const float* __restrict__ bv,
    u16* __restrict__ Qf, u16* __restrict__ Kf, u16* __restrict__ Vf)
{
    __shared__ u16 xs[16][264];
    const int tid = threadIdx.x;
    const int r0 = blockIdx.x * 16;

    #pragma unroll
    for (int i = 0; i < 4; ++i) {
        int c = i * 256 + tid;               // 1024 float4 chunks
        int row = c >> 6, c4 = c & 63;
        float4 v = reinterpret_cast<const float4*>(x + (size_t)(r0 + row) * D_DIM)[c4];
        *reinterpret_cast<ushort4*>(&xs[row][c4 * 4]) =
            make_ushort4(f2bf(v.x), f2bf(v.y), f2bf(v.z), f2bf(v.w));
    }
    __syncthreads();

    const int w = tid >> 6, l = tid & 63, lr = l & 15, lg = l >> 4;
    const int c0 = w * 64;

    bf16x8 a[8];
    #pragma unroll
    for (int kk = 0; kk < 8; ++kk)
        a[kk] = *reinterpret_cast<const bf16x8*>(&xs[lr][kk * 32 + lg * 8]);

    const float* Bs[3] = {bq, bk, bv};

    #pragma unroll
    for (int m = 0; m < 3; ++m) {
        const u16* Wm = Wf + (size_t)m * 65536;
        f32x4 acc[4] = {};
        #pragma unroll
        for (int kk = 0; kk < 8; ++kk) {
            #pragma unroll
            for (int cf = 0; cf < 4; ++cf) {
                bf16x8 wfr = *reinterpret_cast<const bf16x8*>(
                    Wm + fr_qk(w * 4 + cf, kk) + l * 8);
                acc[cf] = __builtin_amdgcn_mfma_f32_16x16x32_bf16(a[kk], wfr, acc[cf], 0, 0, 0);
            }
        }
        if (m < 2) {
            u16* outp = (m == 0) ? Qf : Kf;
            int t = r0 >> 4;
            #pragma unroll
            for (int cf = 0; cf < 4; ++cf) {
                int col = c0 + cf * 16 + lr;
                float bias = Bs[m][col];
                size_t base = fr_qk(t, col >> 5) + ((col >> 3) & 3) * 128 + (col & 7);
                #pragma unroll
                for (int r = 0; r < 4; ++r)
                    outp[base + (lg * 4 + r) * 8] = f2bf(acc[cf][r] + bias);
            }
        } else {
            int p  = (r0 >> 12) * 64 + ((r0 & 4095) >> 6);
            int kb = r0 & 63;                 // key offset in panel (16-aligned)
            #pragma unroll
            for (int cf = 0; cf < 4; ++cf) {
                int d = c0 + cf * 16 + lr;
                float bias = bv[d];
                #pragma unroll
                for (int r = 0; r < 4; ++r) {
                    int key = kb + lg * 4 + r;
                    size_t off = fr_v(p, d >> 4, key >> 5)
                               + ((key >> 3) & 3) * 128 + (d & 15) * 8 + (key & 7);
                    Vf[off] = f2bf(acc[cf][r] + bias);
                }
            }
        }
    }
}

// ---------------- Kernel B: column softmax log-denominators ---------------
// LZ[b,k] = ln( sum_q exp(s[b,q,k]/16) ).  Block = 16 keys x 4 q-quarters.
__global__ __launch_bounds__(256) void col_denom(
    const u16* __restrict__ Qf, const u16* __restrict__ Kf, float* __restrict__ LZ)
{
    __shared__ float zbuf[4][16];
    const int tid = threadIdx.x, blk = blockIdx.x;
    const int w = tid >> 6, l = tid & 63, lr = l & 15, lg = l >> 4;
    const int b  = (blk & 7) >> 1;                  // XCD-cluster batches
    const int k0 = (((blk >> 3) << 1) | (blk & 1)) * 16;

    const int tk = (b * S_LEN + k0) >> 4;
    bf16x8 kreg[8];
    #pragma unroll
    for (int kk = 0; kk < 8; ++kk)
        kreg[kk] = *reinterpret_cast<const bf16x8*>(Kf + fr_qk(tk, kk) + l * 8);

    float Z[4] = {0.f, 0.f, 0.f, 0.f};
    const float SC = 0.0625f;

    for (int qt = 0; qt < 16; ++qt) {
        const int tq = (b * S_LEN + (w * 16 + qt) * 64) >> 4;
        f32x4 acc[4] = {};
        #pragma unroll
        for (int kk = 0; kk < 8; ++kk) {
            #pragma unroll
            for (int cf = 0; cf < 4; ++cf) {
                bf16x8 qfr = *reinterpret_cast<const bf16x8*>(
                    Qf + fr_qk(tq + cf, kk) + l * 8);
                acc[cf] = __builtin_amdgcn_mfma_f32_16x16x32_bf16(kreg[kk], qfr, acc[cf], 0, 0, 0);
            }
        }
        #pragma unroll
        for (int cf = 0; cf < 4; ++cf)
            #pragma unroll
            for (int r = 0; r < 4; ++r)
                Z[r] += __expf(acc[cf][r] * SC);
    }
    #pragma unroll
    for (int r = 0; r < 4; ++r) {
        float z = Z[r];
        z += __shfl_xor(z, 1);
        z += __shfl_xor(z, 2);
        z += __shfl_xor(z, 4);
        z += __shfl_xor(z, 8);
        if (lr == 0) zbuf[w][lg * 4 + r] = z;
    }
    __syncthreads();
    if (tid < 16)
        LZ[b * S_LEN + k0 + tid] =
            logf(zbuf[0][tid] + zbuf[1][tid] + zbuf[2][tid] + zbuf[3][tid]);
}

// ---------------- Kernel C: out = (exp(S)/Z) @ V --------------------------
// Block = one 16-query tile x 4 key-quarters (one per wave); all operand
// loads are coalesced 1KB fragment loads.
__global__ __launch_bounds__(256, 4) void attn_out(
    const u16* __restrict__ Qf, const u16* __restrict__ Kf, const u16* __restrict__ Vf,
    const float* __restrict__ LZ, float* __restrict__ out)
{
    __shared__ __align__(16) char smem[32768];
    const int tid = threadIdx.x, blk = blockIdx.x;
    const int b  = (blk & 7) >> 1;                  // XCD-cluster batches
    const int qs = ((blk >> 3) << 1) | (blk & 1);   // 0..255 q16-tile
    const int w = tid >> 6, l = tid & 63, lr = l & 15, lg = l >> 4;
    const int q0 = qs * 16;

    u16* ps = reinterpret_cast<u16*>(smem) + w * 1152;   // [16][72] per wave

    const int tq = (b * S_LEN + q0) >> 4;
    bf16x8 qreg[8];
    #pragma unroll
    for (int kk = 0; kk < 8; ++kk)
        qreg[kk] = *reinterpret_cast<const bf16x8*>(Qf + fr_qk(tq, kk) + l * 8);

    f32x4 oacc[16] = {};
    const float SC = 0.0625f;

    for (int kt = w * 16; kt < w * 16 + 16; ++kt) {
        const int kbase = kt * 64;
        const int tk = (b * S_LEN + kbase) >> 4;
        f32x4 sacc[4] = {};
        #pragma unroll
        for (int kk = 0; kk < 8; ++kk) {
            #pragma unroll
            for (int cf = 0; cf < 4; ++cf) {
                bf16x8 kfr = *reinterpret_cast<const bf16x8*>(
                    Kf + fr_qk(tk + cf, kk) + l * 8);
                sacc[cf] = __builtin_amdgcn_mfma_f32_16x16x32_bf16(qreg[kk], kfr, sacc[cf], 0, 0, 0);
            }
        }
        #pragma unroll
        for (int cf = 0; cf < 4; ++cf) {
            float L = LZ[b * S_LEN + kbase + cf * 16 + lr];
            #pragma unroll
            for (int r = 0; r < 4; ++r) {
                float p = __expf(fmaf(sacc[cf][r], SC, -L));
                ps[(lg * 4 + r) * 72 + cf * 16 + lr] = f2bf(p);
            }
        }
        const int pnl = b * 64 + kt;
        #pragma unroll
        for (int kk2 = 0; kk2 < 2; ++kk2) {
            bf16x8 af = *reinterpret_cast<const bf16x8*>(&ps[lr * 72 + kk2 * 32 + lg * 8]);
            #pragma unroll
            for (int cf2 = 0; cf2 < 16; ++cf2) {
                bf16x8 vfr = *reinterpret_cast<const bf16x8*>(
                    Vf + fr_v(pnl, cf2, kk2) + l * 8);
                oacc[cf2] = __builtin_amdgcn_mfma_f32_16x16x32_bf16(af, vfr, oacc[cf2], 0, 0, 0);
            }
        }
    }

    // ---- cross-wave reduction of oacc (reuse smem) ----
    float* red = reinterpret_cast<float*>(smem);     // 2 x 4096 f32
    __syncthreads();
    if (w == 1) {
        #pragma unroll
        for (int c = 0; c < 16; ++c)
            *reinterpret_cast<f32x4*>(&red[c * 256 + l * 4]) = oacc[c];
    }
    if (w == 3) {
        #pragma unroll
        for (int c = 0; c < 16; ++c)
            *reinterpret_cast<f32x4*>(&red[4096 + c * 256 + l * 4]) = oacc[c];
    }
    __syncthreads();
    if (w == 0) {
        #pragma unroll
        for (int c = 0; c < 16; ++c)
            oacc[c] += *reinterpret_cast<f32x4*>(&red[c * 256 + l * 4]);
    }
    if (w == 2) {
        #pragma unroll
        for (int c = 0; c < 16; ++c)
            oacc[c] += *reinterpret_cast<f32x4*>(&red[4096 + c * 256 + l * 4]);
    }
    __syncthreads();
    if (w == 2) {
        #pragma unroll
        for (int c = 0; c < 16; ++c)
            *reinterpret_cast<f32x4*>(&red[c * 256 + l * 4]) = oacc[c];
    }
    __syncthreads();
    if (w == 0) {
        #pragma unroll
        for (int c = 0; c < 16; ++c)
            oacc[c] += *reinterpret_cast<f32x4*>(&red[c * 256 + l * 4]);
        #pragma unroll
        for (int c = 0; c < 16; ++c) {
            #pragma unroll
            for (int r = 0; r < 4; ++r) {
                int row = q0 + lg * 4 + r;
                out[((size_t)(b * S_LEN + row)) * D_DIM + c * 16 + lr] = oacc[c][r];
            }
        }
    }
}

// ---------------- launcher ------------------------------------------------
extern "C" void kernel_launch(void* const* d_in, const int* in_sizes, int n_in,
                              void* d_out, int out_size, void* d_ws, size_t ws_size,
                              hipStream_t stream) {
    const float* x  = (const float*)d_in[0];
    const float* Wq = (const float*)d_in[1];
    const float* bq = (const float*)d_in[2];
    const float* Wk = (const float*)d_in[3];
    const float* bk = (const float*)d_in[4];
    const float* Wv = (const float*)d_in[5];
    const float* bv = (const float*)d_in[6];
    float* out = (float*)d_out;

    u16* Qf = (u16*)d_ws;                            // 8 MB (fragment layout)
    u16* Kf = Qf + (size_t)NROW * D_DIM;             // 8 MB
    u16* Vf = Kf + (size_t)NROW * D_DIM;             // 8 MB
    float* LZ = (float*)(Vf + (size_t)NROW * D_DIM); // 64 KB
    u16* Wf = (u16*)(LZ + NROW);                     // 384 KB

    wconv<<<96, 256, 0, stream>>>(Wq, Wk, Wv, Wf);
    qkv_proj<<<NROW / 16, 256, 0, stream>>>(x, Wf, bq, bk, bv, Qf, Kf, Vf);
    col_denom<<<1024, 256, 0, stream>>>(Qf, Kf, LZ);
    attn_out<<<1024, 256, 0, stream>>>(Qf, Kf, Vf, LZ, out);
}

// Round 4
// 352.647 us; speedup vs baseline: 2.1775x; 1.0275x over previous
//
#include <hip/hip_runtime.h>

typedef short bf16x8 __attribute__((ext_vector_type(8)));
typedef float f32x4 __attribute__((ext_vector_type(4)));
typedef unsigned short u16;

#define S_LEN 4096
#define D_DIM 256
#define NROW  16384   // B*S

__device__ __forceinline__ u16 f2bf(float f) {
    union { float f; unsigned u; } v; v.f = f;
    unsigned r = v.u + 0x7FFFu + ((v.u >> 16) & 1u);
    return (u16)(r >> 16);
}

// Fragment-linear layouts (bf16):
//  Q/K/W: row-tile t (16 rows), kk (32-k chunk): frag = t*4096 + kk*512,
//         elem(row_local, col) at ((col>>3)&3)*128 + row_local*8 + (col&7).
//         Lane l reads frag + l*8 -> row=l&15, k=(l>>4)*8+e. 1KB coalesced.
//  V^T:   panel p = b*64+kt (64 keys x 256 d = 32KB): frag(dtile,kk2) =
//         p*16384 + (dtile*2+kk2)*512.
__device__ __forceinline__ size_t fr_qk(int t, int kk) {
    return (size_t)t * 4096 + kk * 512;
}
__device__ __forceinline__ size_t fr_v(int p, int dt, int kk2) {
    return (size_t)p * 16384 + (dt * 2 + kk2) * 512;
}

// ---------------- Kernel W: W f32 -> bf16 fragments -----------------------
__global__ __launch_bounds__(256) void wconv(
    const float* __restrict__ Wq, const float* __restrict__ Wk,
    const float* __restrict__ Wv, u16* __restrict__ Wf)
{
    int i = blockIdx.x * 256 + threadIdx.x;   // 24576 threads
    int m = i >> 13;
    int idx = i & 8191;
    int ocol = idx >> 5;                      // 0..255 (row of W = out col)
    int d0 = (idx & 31) * 8;
    const float* s = (m == 0 ? Wq : (m == 1 ? Wk : Wv)) + ocol * 256 + d0;
    float4 v0 = *reinterpret_cast<const float4*>(s);
    float4 v1 = *reinterpret_cast<const float4*>(s + 4);
    union { ushort4 h[2]; int4 q; } t;
    t.h[0] = make_ushort4(f2bf(v0.x), f2bf(v0.y), f2bf(v0.z), f2bf(v0.w));
    t.h[1] = make_ushort4(f2bf(v1.x), f2bf(v1.y), f2bf(v1.z), f2bf(v1.w));
    size_t off = (size_t)m * 65536 + fr_qk(ocol >> 4, d0 >> 5)
               + ((d0 >> 3) & 3) * 128 + (ocol & 15) * 8;
    *reinterpret_cast<int4*>(Wf + off) = t.q;
}

// ---------------- Kernel A: QKV projection (32 rows/block) ----------------
__global__ __launch_bounds__(256) void qkv_proj(
    const float* __restrict__ x, const u16* __restrict__ Wf,
    const float* __restrict__ bq, const float* __restrict__ bk,
    const float* __restrict__ bv,
    u16* __restrict__ Qf, u16* __restrict__ Kf, u16* __restrict__ Vf)
{
    __shared__ u16 xs[32][264];
    const int tid = threadIdx.x;
    const int r0 = blockIdx.x * 32;

    #pragma unroll
    for (int i = 0; i < 8; ++i) {
        int c = i * 256 + tid;               // 2048 float4 chunks
        int row = c >> 6, c4 = c & 63;
        float4 v = reinterpret_cast<const float4*>(x + (size_t)(r0 + row) * D_DIM)[c4];
        *reinterpret_cast<ushort4*>(&xs[row][c4 * 4]) =
            make_ushort4(f2bf(v.x), f2bf(v.y), f2bf(v.z), f2bf(v.w));
    }
    __syncthreads();

    const int w = tid >> 6, l = tid & 63, lr = l & 15, lg = l >> 4;
    const int c0 = w * 64;

    bf16x8 a[2][8];
    #pragma unroll
    for (int qs = 0; qs < 2; ++qs)
        #pragma unroll
        for (int kk = 0; kk < 8; ++kk)
            a[qs][kk] = *reinterpret_cast<const bf16x8*>(&xs[qs * 16 + lr][kk * 32 + lg * 8]);

    const float* Bs[3] = {bq, bk, bv};

    #pragma unroll
    for (int m = 0; m < 3; ++m) {
        const u16* Wm = Wf + (size_t)m * 65536;
        f32x4 acc[2][4] = {};
        #pragma unroll
        for (int kk = 0; kk < 8; ++kk) {
            #pragma unroll
            for (int cf = 0; cf < 4; ++cf) {
                bf16x8 wfr = *reinterpret_cast<const bf16x8*>(
                    Wm + fr_qk(w * 4 + cf, kk) + l * 8);
                acc[0][cf] = __builtin_amdgcn_mfma_f32_16x16x32_bf16(a[0][kk], wfr, acc[0][cf], 0, 0, 0);
                acc[1][cf] = __builtin_amdgcn_mfma_f32_16x16x32_bf16(a[1][kk], wfr, acc[1][cf], 0, 0, 0);
            }
        }
        if (m < 2) {
            u16* outp = (m == 0) ? Qf : Kf;
            int t = r0 >> 4;
            #pragma unroll
            for (int qs = 0; qs < 2; ++qs) {
                #pragma unroll
                for (int cf = 0; cf < 4; ++cf) {
                    int col = c0 + cf * 16 + lr;
                    float bias = Bs[m][col];
                    size_t base = fr_qk(t + qs, col >> 5) + ((col >> 3) & 3) * 128 + (col & 7);
                    #pragma unroll
                    for (int r = 0; r < 4; ++r)
                        outp[base + (lg * 4 + r) * 8] = f2bf(acc[qs][cf][r] + bias);
                }
            }
        } else {
            int p  = (r0 >> 12) * 64 + ((r0 & 4095) >> 6);
            int kb = r0 & 63;
            #pragma unroll
            for (int qs = 0; qs < 2; ++qs) {
                #pragma unroll
                for (int cf = 0; cf < 4; ++cf) {
                    int d = c0 + cf * 16 + lr;
                    float bias = bv[d];
                    #pragma unroll
                    for (int r = 0; r < 4; ++r) {
                        int key = kb + qs * 16 + lg * 4 + r;
                        size_t off = fr_v(p, d >> 4, key >> 5)
                                   + ((key >> 3) & 3) * 128 + (d & 15) * 8 + (key & 7);
                        Vf[off] = f2bf(acc[qs][cf][r] + bias);
                    }
                }
            }
        }
    }
}

// ---------------- Kernel B: column softmax log-denominators ---------------
// LZ[b,k] = ln( sum_q exp(s[b,q,k]/16) ).  Block = 32 keys x 4 q-quarters;
// each wave holds 32 keys in regs, every Q fragment feeds 2 MFMAs.
__global__ __launch_bounds__(256) void col_denom(
    const u16* __restrict__ Qf, const u16* __restrict__ Kf, float* __restrict__ LZ)
{
    __shared__ float zbuf[4][32];
    const int tid = threadIdx.x, blk = blockIdx.x;
    const int w = tid >> 6, l = tid & 63, lr = l & 15, lg = l >> 4;
    const int b  = (blk & 7) >> 1;                  // XCD-cluster batches
    const int k0 = (((blk >> 3) << 1) | (blk & 1)) * 32;

    const int tk = (b * S_LEN + k0) >> 4;
    bf16x8 kreg[2][8];
    #pragma unroll
    for (int ks = 0; ks < 2; ++ks)
        #pragma unroll
        for (int kk = 0; kk < 8; ++kk)
            kreg[ks][kk] = *reinterpret_cast<const bf16x8*>(Kf + fr_qk(tk + ks, kk) + l * 8);

    float Z[2][4] = {};
    const float SC = 0.0625f;

    for (int qt = 0; qt < 16; ++qt) {
        const int tq = (b * S_LEN + (w * 16 + qt) * 64) >> 4;
        f32x4 acc[2][4] = {};
        #pragma unroll
        for (int kk = 0; kk < 8; ++kk) {
            #pragma unroll
            for (int cf = 0; cf < 4; ++cf) {
                bf16x8 qfr = *reinterpret_cast<const bf16x8*>(
                    Qf + fr_qk(tq + cf, kk) + l * 8);
                acc[0][cf] = __builtin_amdgcn_mfma_f32_16x16x32_bf16(kreg[0][kk], qfr, acc[0][cf], 0, 0, 0);
                acc[1][cf] = __builtin_amdgcn_mfma_f32_16x16x32_bf16(kreg[1][kk], qfr, acc[1][cf], 0, 0, 0);
            }
        }
        #pragma unroll
        for (int ks = 0; ks < 2; ++ks)
            #pragma unroll
            for (int cf = 0; cf < 4; ++cf)
                #pragma unroll
                for (int r = 0; r < 4; ++r)
                    Z[ks][r] += __expf(acc[ks][cf][r] * SC);
    }
    #pragma unroll
    for (int ks = 0; ks < 2; ++ks) {
        #pragma unroll
        for (int r = 0; r < 4; ++r) {
            float z = Z[ks][r];
            z += __shfl_xor(z, 1);
            z += __shfl_xor(z, 2);
            z += __shfl_xor(z, 4);
            z += __shfl_xor(z, 8);
            if (lr == 0) zbuf[w][ks * 16 + lg * 4 + r] = z;
        }
    }
    __syncthreads();
    if (tid < 32)
        LZ[b * S_LEN + k0 + tid] =
            logf(zbuf[0][tid] + zbuf[1][tid] + zbuf[2][tid] + zbuf[3][tid]);
}

// ---------------- Kernel C: out = (exp(S)/Z) @ V --------------------------
// Block = one 32-query tile x 4 key-quarters (one per wave). Every K/V
// fragment feeds 2 MFMAs (two 16-query row sets).
__global__ __launch_bounds__(256, 2) void attn_out(
    const u16* __restrict__ Qf, const u16* __restrict__ Kf, const u16* __restrict__ Vf,
    const float* __restrict__ LZ, float* __restrict__ out)
{
    __shared__ __align__(16) char smem[32768];
    const int tid = threadIdx.x, blk = blockIdx.x;
    const int b  = (blk & 7) >> 1;                  // XCD-cluster batches
    const int qs_i = ((blk >> 3) << 1) | (blk & 1); // 0..127 q32-tile
    const int w = tid >> 6, l = tid & 63, lr = l & 15, lg = l >> 4;
    const int q0 = qs_i * 32;

    u16* ps = reinterpret_cast<u16*>(smem) + w * 2304;   // [32][72] per wave

    const int tq = (b * S_LEN + q0) >> 4;
    bf16x8 qreg[2][8];
    #pragma unroll
    for (int qs = 0; qs < 2; ++qs)
        #pragma unroll
        for (int kk = 0; kk < 8; ++kk)
            qreg[qs][kk] = *reinterpret_cast<const bf16x8*>(Qf + fr_qk(tq + qs, kk) + l * 8);

    f32x4 oacc[2][16] = {};
    const float SC = 0.0625f;

    for (int kt = w * 16; kt < w * 16 + 16; ++kt) {
        const int kbase = kt * 64;
        const int tk = (b * S_LEN + kbase) >> 4;
        f32x4 sacc[2][4] = {};
        #pragma unroll
        for (int kk = 0; kk < 8; ++kk) {
            #pragma unroll
            for (int cf = 0; cf < 4; ++cf) {
                bf16x8 kfr = *reinterpret_cast<const bf16x8*>(
                    Kf + fr_qk(tk + cf, kk) + l * 8);
                sacc[0][cf] = __builtin_amdgcn_mfma_f32_16x16x32_bf16(qreg[0][kk], kfr, sacc[0][cf], 0, 0, 0);
                sacc[1][cf] = __builtin_amdgcn_mfma_f32_16x16x32_bf16(qreg[1][kk], kfr, sacc[1][cf], 0, 0, 0);
            }
        }
        #pragma unroll
        for (int cf = 0; cf < 4; ++cf) {
            float L = LZ[b * S_LEN + kbase + cf * 16 + lr];
            #pragma unroll
            for (int qs = 0; qs < 2; ++qs) {
                #pragma unroll
                for (int r = 0; r < 4; ++r) {
                    float p = __expf(fmaf(sacc[qs][cf][r], SC, -L));
                    ps[(qs * 16 + lg * 4 + r) * 72 + cf * 16 + lr] = f2bf(p);
                }
            }
        }
        const int pnl = b * 64 + kt;
        #pragma unroll
        for (int kk2 = 0; kk2 < 2; ++kk2) {
            bf16x8 af0 = *reinterpret_cast<const bf16x8*>(&ps[lr * 72 + kk2 * 32 + lg * 8]);
            bf16x8 af1 = *reinterpret_cast<const bf16x8*>(&ps[(16 + lr) * 72 + kk2 * 32 + lg * 8]);
            #pragma unroll
            for (int cf2 = 0; cf2 < 16; ++cf2) {
                bf16x8 vfr = *reinterpret_cast<const bf16x8*>(
                    Vf + fr_v(pnl, cf2, kk2) + l * 8);
                oacc[0][cf2] = __builtin_amdgcn_mfma_f32_16x16x32_bf16(af0, vfr, oacc[0][cf2], 0, 0, 0);
                oacc[1][cf2] = __builtin_amdgcn_mfma_f32_16x16x32_bf16(af1, vfr, oacc[1][cf2], 0, 0, 0);
            }
        }
    }

    // ---- cross-wave reduction of oacc (32 KB buffer = one wave's oacc) ----
    float* red = reinterpret_cast<float*>(smem);
    __syncthreads();
    if (w == 1) {
        #pragma unroll
        for (int qs = 0; qs < 2; ++qs)
            #pragma unroll
            for (int c = 0; c < 16; ++c)
                *reinterpret_cast<f32x4*>(&red[(qs * 16 + c) * 256 + l * 4]) = oacc[qs][c];
    }
    __syncthreads();
    if (w == 0) {
        #pragma unroll
        for (int qs = 0; qs < 2; ++qs)
            #pragma unroll
            for (int c = 0; c < 16; ++c)
                oacc[qs][c] += *reinterpret_cast<f32x4*>(&red[(qs * 16 + c) * 256 + l * 4]);
    }
    __syncthreads();
    if (w == 3) {
        #pragma unroll
        for (int qs = 0; qs < 2; ++qs)
            #pragma unroll
            for (int c = 0; c < 16; ++c)
                *reinterpret_cast<f32x4*>(&red[(qs * 16 + c) * 256 + l * 4]) = oacc[qs][c];
    }
    __syncthreads();
    if (w == 2) {
        #pragma unroll
        for (int qs = 0; qs < 2; ++qs)
            #pragma unroll
            for (int c = 0; c < 16; ++c)
                oacc[qs][c] += *reinterpret_cast<f32x4*>(&red[(qs * 16 + c) * 256 + l * 4]);
    }
    __syncthreads();
    if (w == 2) {
        #pragma unroll
        for (int qs = 0; qs < 2; ++qs)
            #pragma unroll
            for (int c = 0; c < 16; ++c)
                *reinterpret_cast<f32x4*>(&red[(qs * 16 + c) * 256 + l * 4]) = oacc[qs][c];
    }
    __syncthreads();
    if (w == 0) {
        #pragma unroll
        for (int qs = 0; qs < 2; ++qs) {
            #pragma unroll
            for (int c = 0; c < 16; ++c) {
                oacc[qs][c] += *reinterpret_cast<f32x4*>(&red[(qs * 16 + c) * 256 + l * 4]);
                #pragma unroll
                for (int r = 0; r < 4; ++r) {
                    int row = q0 + qs * 16 + lg * 4 + r;
                    out[((size_t)(b * S_LEN + row)) * D_DIM + c * 16 + lr] = oacc[qs][c][r];
                }
            }
        }
    }
}

// ---------------- launcher ------------------------------------------------
extern "C" void kernel_launch(void* const* d_in, const int* in_sizes, int n_in,
                              void* d_out, int out_size, void* d_ws, size_t ws_size,
                              hipStream_t stream) {
    const float* x  = (const float*)d_in[0];
    const float* Wq = (const float*)d_in[1];
    const float* bq = (const float*)d_in[2];
    const float* Wk = (const float*)d_in[3];
    const float* bk = (const float*)d_in[4];
    const float* Wv = (const float*)d_in[5];
    const float* bv = (const float*)d_in[6];
    float* out = (float*)d_out;

    u16* Qf = (u16*)d_ws;                            // 8 MB (fragment layout)
    u16* Kf = Qf + (size_t)NROW * D_DIM;             // 8 MB
    u16* Vf = Kf + (size_t)NROW * D_DIM;             // 8 MB
    float* LZ = (float*)(Vf + (size_t)NROW * D_DIM); // 64 KB
    u16* Wf = (u16*)(LZ + NROW);                     // 384 KB

    wconv<<<96, 256, 0, stream>>>(Wq, Wk, Wv, Wf);
    qkv_proj<<<NROW / 32, 256, 0, stream>>>(x, Wf, bq, bk, bv, Qf, Kf, Vf);
    col_denom<<<512, 256, 0, stream>>>(Qf, Kf, LZ);
    attn_out<<<512, 256, 0, stream>>>(Qf, Kf, Vf, LZ, out);
}

// Round 5
// 219.788 us; speedup vs baseline: 3.4938x; 1.6045x over previous
//
#include <hip/hip_runtime.h>

typedef short bf16x8 __attribute__((ext_vector_type(8)));
typedef float f32x4 __attribute__((ext_vector_type(4)));
typedef unsigned short u16;

#define S_LEN 4096
#define D_DIM 256
#define NROW  16384   // B*S

__device__ __forceinline__ u16 f2bf(float f) {
    union { float f; unsigned u; } v; v.f = f;
    unsigned r = v.u + 0x7FFFu + ((v.u >> 16) & 1u);
    return (u16)(r >> 16);
}

// Fragment-linear layouts (bf16):
//  Q/K/W: row-tile t (16 rows), kk (32-k chunk): frag = t*4096 + kk*512,
//         elem(row_local, col) at ((col>>3)&3)*128 + row_local*8 + (col&7).
//         Lane l reads frag + l*8 -> row=l&15, k=(l>>4)*8+e. 1KB coalesced.
//  V^T:   panel p = b*64+kt (64 keys x 256 d = 32KB): frag(dtile,kk2) =
//         p*16384 + (dtile*2+kk2)*512.
//  A 64-row K/Q panel (4 tiles) is 32KB CONTIGUOUS: frag f=cf*8+kk at
//  panel_base + f*512.  V panel likewise: frag f=dt*2+kk2 at p*16384+f*512.
__device__ __forceinline__ size_t fr_qk(int t, int kk) {
    return (size_t)t * 4096 + kk * 512;
}
__device__ __forceinline__ size_t fr_v(int p, int dt, int kk2) {
    return (size_t)p * 16384 + (dt * 2 + kk2) * 512;
}

// async global->LDS, 16B/lane: lane l's 16B from g+l*8(u16) lands at lds+l*16.
__device__ __forceinline__ void gll16(const u16* g, u16* l) {
    __builtin_amdgcn_global_load_lds(
        (const __attribute__((address_space(1))) unsigned int*)g,
        (__attribute__((address_space(3))) unsigned int*)l, 16, 0, 0);
}

// ---------------- Kernel W: W f32 -> bf16 fragments -----------------------
__global__ __launch_bounds__(256) void wconv(
    const float* __restrict__ Wq, const float* __restrict__ Wk,
    const float* __restrict__ Wv, u16* __restrict__ Wf)
{
    int i = blockIdx.x * 256 + threadIdx.x;   // 24576 threads
    int m = i >> 13;
    int idx = i & 8191;
    int ocol = idx >> 5;                      // 0..255 (row of W = out col)
    int d0 = (idx & 31) * 8;
    const float* s = (m == 0 ? Wq : (m == 1 ? Wk : Wv)) + ocol * 256 + d0;
    float4 v0 = *reinterpret_cast<const float4*>(s);
    float4 v1 = *reinterpret_cast<const float4*>(s + 4);
    union { ushort4 h[2]; int4 q; } t;
    t.h[0] = make_ushort4(f2bf(v0.x), f2bf(v0.y), f2bf(v0.z), f2bf(v0.w));
    t.h[1] = make_ushort4(f2bf(v1.x), f2bf(v1.y), f2bf(v1.z), f2bf(v1.w));
    size_t off = (size_t)m * 65536 + fr_qk(ocol >> 4, d0 >> 5)
               + ((d0 >> 3) & 3) * 128 + (ocol & 15) * 8;
    *reinterpret_cast<int4*>(Wf + off) = t.q;
}

// ---------------- Kernel A: QKV projection (32 rows/block) ----------------
__global__ __launch_bounds__(256) void qkv_proj(
    const float* __restrict__ x, const u16* __restrict__ Wf,
    const float* __restrict__ bq, const float* __restrict__ bk,
    const float* __restrict__ bv,
    u16* __restrict__ Qf, u16* __restrict__ Kf, u16* __restrict__ Vf)
{
    __shared__ u16 xs[32][264];
    const int tid = threadIdx.x;
    const int r0 = blockIdx.x * 32;

    #pragma unroll
    for (int i = 0; i < 8; ++i) {
        int c = i * 256 + tid;               // 2048 float4 chunks
        int row = c >> 6, c4 = c & 63;
        float4 v = reinterpret_cast<const float4*>(x + (size_t)(r0 + row) * D_DIM)[c4];
        *reinterpret_cast<ushort4*>(&xs[row][c4 * 4]) =
            make_ushort4(f2bf(v.x), f2bf(v.y), f2bf(v.z), f2bf(v.w));
    }
    __syncthreads();

    const int w = tid >> 6, l = tid & 63, lr = l & 15, lg = l >> 4;
    const int c0 = w * 64;

    bf16x8 a[2][8];
    #pragma unroll
    for (int qs = 0; qs < 2; ++qs)
        #pragma unroll
        for (int kk = 0; kk < 8; ++kk)
            a[qs][kk] = *reinterpret_cast<const bf16x8*>(&xs[qs * 16 + lr][kk * 32 + lg * 8]);

    const float* Bs[3] = {bq, bk, bv};

    #pragma unroll
    for (int m = 0; m < 3; ++m) {
        const u16* Wm = Wf + (size_t)m * 65536;
        f32x4 acc[2][4] = {};
        #pragma unroll
        for (int kk = 0; kk < 8; ++kk) {
            #pragma unroll
            for (int cf = 0; cf < 4; ++cf) {
                bf16x8 wfr = *reinterpret_cast<const bf16x8*>(
                    Wm + fr_qk(w * 4 + cf, kk) + l * 8);
                acc[0][cf] = __builtin_amdgcn_mfma_f32_16x16x32_bf16(a[0][kk], wfr, acc[0][cf], 0, 0, 0);
                acc[1][cf] = __builtin_amdgcn_mfma_f32_16x16x32_bf16(a[1][kk], wfr, acc[1][cf], 0, 0, 0);
            }
        }
        if (m < 2) {
            u16* outp = (m == 0) ? Qf : Kf;
            int t = r0 >> 4;
            #pragma unroll
            for (int qs = 0; qs < 2; ++qs) {
                #pragma unroll
                for (int cf = 0; cf < 4; ++cf) {
                    int col = c0 + cf * 16 + lr;
                    float bias = Bs[m][col];
                    size_t base = fr_qk(t + qs, col >> 5) + ((col >> 3) & 3) * 128 + (col & 7);
                    #pragma unroll
                    for (int r = 0; r < 4; ++r)
                        outp[base + (lg * 4 + r) * 8] = f2bf(acc[qs][cf][r] + bias);
                }
            }
        } else {
            int p  = (r0 >> 12) * 64 + ((r0 & 4095) >> 6);
            int kb = r0 & 63;
            #pragma unroll
            for (int qs = 0; qs < 2; ++qs) {
                #pragma unroll
                for (int cf = 0; cf < 4; ++cf) {
                    int d = c0 + cf * 16 + lr;
                    float bias = bv[d];
                    #pragma unroll
                    for (int r = 0; r < 4; ++r) {
                        int key = kb + qs * 16 + lg * 4 + r;
                        size_t off = fr_v(p, d >> 4, key >> 5)
                                   + ((key >> 3) & 3) * 128 + (d & 15) * 8 + (key & 7);
                        Vf[off] = f2bf(acc[qs][cf][r] + bias);
                    }
                }
            }
        }
    }
}

// ---------------- Kernel B: column softmax log-denominators ---------------
// LZ[b,k] = ln( sum_q exp(s[b,q,k]/16) ).  Block = 64 keys (wave w owns 16,
// held in regs); Q staged in LDS 2-phase via global_load_lds (double-buffer).
__global__ __launch_bounds__(256) void col_denom(
    const u16* __restrict__ Qf, const u16* __restrict__ Kf, float* __restrict__ LZ)
{
    __shared__ __align__(16) u16 Qls[2][16384];   // 2 x 32KB q-panels
    const int tid = threadIdx.x, blk = blockIdx.x;
    const int b = (blk >> 1) & 3;                 // XCD-clustered decode
    const int t = ((blk >> 3) << 1) | (blk & 1);  // key-tile 0..63
    const int w = tid >> 6, l = tid & 63, lr = l & 15, lg = l >> 4;
    const int k0 = t * 64;
    const int base_tq = b * 256;                  // (b*S_LEN)/16

    const int tkw = base_tq + (k0 >> 4) + w;
    bf16x8 kreg[8];
    #pragma unroll
    for (int kk = 0; kk < 8; ++kk)
        kreg[kk] = *reinterpret_cast<const bf16x8*>(Kf + fr_qk(tkw, kk) + l * 8);

    #define STAGE_Q(qt, nb) do { \
        const u16* g_ = Qf + ((size_t)(base_tq + (qt) * 4)) * 4096 + (w * 8) * 512 + l * 8; \
        u16* d_ = &Qls[nb][(w * 8) * 512]; \
        _Pragma("unroll") \
        for (int f_ = 0; f_ < 8; ++f_) gll16(g_ + f_ * 512, d_ + f_ * 512); \
    } while (0)

    STAGE_Q(0, 0);
    __syncthreads();

    float Z[4] = {};
    const float SC = 0.0625f;

    for (int qt = 0; qt < 64; ++qt) {
        const int cur = qt & 1;
        if (qt < 63) STAGE_Q(qt + 1, cur ^ 1);

        f32x4 acc[4] = {};
        #pragma unroll
        for (int kk = 0; kk < 8; ++kk) {
            #pragma unroll
            for (int cf = 0; cf < 4; ++cf) {
                bf16x8 qfr = *reinterpret_cast<const bf16x8*>(
                    &Qls[cur][(cf * 8 + kk) * 512 + l * 8]);
                acc[cf] = __builtin_amdgcn_mfma_f32_16x16x32_bf16(kreg[kk], qfr, acc[cf], 0, 0, 0);
            }
        }
        #pragma unroll
        for (int cf = 0; cf < 4; ++cf)
            #pragma unroll
            for (int r = 0; r < 4; ++r)
                Z[r] += __expf(acc[cf][r] * SC);
        __syncthreads();
    }

    #pragma unroll
    for (int r = 0; r < 4; ++r) {
        float z = Z[r];
        z += __shfl_xor(z, 1);
        z += __shfl_xor(z, 2);
        z += __shfl_xor(z, 4);
        z += __shfl_xor(z, 8);
        if (lr == 0) LZ[b * S_LEN + k0 + w * 16 + lg * 4 + r] = logf(z);
    }
    #undef STAGE_Q
}

// ---------------- Kernel C: out = (exp(S)/Z) @ V --------------------------
// Block = 64 q rows (wave w owns 16 -> no cross-wave reduce). All waves walk
// all 64 key-panels; K+V double-buffered in LDS, staged 2-phase via
// global_load_lds (stage kt+1 at top of body, one barrier per kt).
__global__ __launch_bounds__(256) void attn_out(
    const u16* __restrict__ Qf, const u16* __restrict__ Kf, const u16* __restrict__ Vf,
    const float* __restrict__ LZ, float* __restrict__ out)
{
    __shared__ __align__(16) u16 Kls[2][16384];   // 2 x 32KB K panels
    __shared__ __align__(16) u16 Vls[2][16384];   // 2 x 32KB V^T panels
    __shared__ __align__(16) u16 ps[4][1152];     // per-wave P tile [16][72]

    const int tid = threadIdx.x, blk = blockIdx.x;
    const int b = (blk >> 1) & 3;                 // XCD-clustered decode
    const int t = ((blk >> 3) << 1) | (blk & 1);  // q-tile 0..63
    const int w = tid >> 6, l = tid & 63, lr = l & 15, lg = l >> 4;
    const int q0 = t * 64 + w * 16;
    const int base_tk = b * 256;                  // (b*S_LEN)/16

    const int tq = base_tk + (q0 >> 4);
    bf16x8 qreg[8];
    #pragma unroll
    for (int kk = 0; kk < 8; ++kk)
        qreg[kk] = *reinterpret_cast<const bf16x8*>(Qf + fr_qk(tq, kk) + l * 8);

    // wave 0,1 stage K panel halves; wave 2,3 stage V panel halves.
    #define STAGE_KV(kt, nb) do { \
        if (w < 2) { \
            const u16* g_ = Kf + ((size_t)(base_tk + (kt) * 4)) * 4096 + (w * 16) * 512 + l * 8; \
            u16* d_ = &Kls[nb][(w * 16) * 512]; \
            _Pragma("unroll") \
            for (int f_ = 0; f_ < 16; ++f_) gll16(g_ + f_ * 512, d_ + f_ * 512); \
        } else { \
            const u16* g_ = Vf + ((size_t)(b * 64 + (kt))) * 16384 + ((w - 2) * 16) * 512 + l * 8; \
            u16* d_ = &Vls[nb][((w - 2) * 16) * 512]; \
            _Pragma("unroll") \
            for (int f_ = 0; f_ < 16; ++f_) gll16(g_ + f_ * 512, d_ + f_ * 512); \
        } \
    } while (0)

    STAGE_KV(0, 0);
    __syncthreads();

    f32x4 oacc[16] = {};
    const float SC = 0.0625f;

    for (int kt = 0; kt < 64; ++kt) {
        const int cur = kt & 1;
        if (kt < 63) STAGE_KV(kt + 1, cur ^ 1);

        float Lv[4];
        #pragma unroll
        for (int cf = 0; cf < 4; ++cf)
            Lv[cf] = LZ[b * S_LEN + kt * 64 + cf * 16 + lr];

        // QK^T from staged K
        f32x4 sacc[4] = {};
        #pragma unroll
        for (int kk = 0; kk < 8; ++kk) {
            #pragma unroll
            for (int cf = 0; cf < 4; ++cf) {
                bf16x8 kfr = *reinterpret_cast<const bf16x8*>(
                    &Kls[cur][(cf * 8 + kk) * 512 + l * 8]);
                sacc[cf] = __builtin_amdgcn_mfma_f32_16x16x32_bf16(qreg[kk], kfr, sacc[cf], 0, 0, 0);
            }
        }
        // P = exp(s/16 - LZ) -> per-wave LDS (A-operand layout)
        #pragma unroll
        for (int cf = 0; cf < 4; ++cf) {
            #pragma unroll
            for (int r = 0; r < 4; ++r) {
                float p = __expf(fmaf(sacc[cf][r], SC, -Lv[cf]));
                ps[w][(lg * 4 + r) * 72 + cf * 16 + lr] = f2bf(p);
            }
        }
        // PV from staged V^T
        #pragma unroll
        for (int kk2 = 0; kk2 < 2; ++kk2) {
            bf16x8 af = *reinterpret_cast<const bf16x8*>(&ps[w][lr * 72 + kk2 * 32 + lg * 8]);
            #pragma unroll
            for (int cf2 = 0; cf2 < 16; ++cf2) {
                bf16x8 vfr = *reinterpret_cast<const bf16x8*>(
                    &Vls[cur][(cf2 * 2 + kk2) * 512 + l * 8]);
                oacc[cf2] = __builtin_amdgcn_mfma_f32_16x16x32_bf16(af, vfr, oacc[cf2], 0, 0, 0);
            }
        }
        __syncthreads();
    }

    #pragma unroll
    for (int cf2 = 0; cf2 < 16; ++cf2) {
        #pragma unroll
        for (int r = 0; r < 4; ++r) {
            int row = q0 + lg * 4 + r;
            out[((size_t)(b * S_LEN + row)) * D_DIM + cf2 * 16 + lr] = oacc[cf2][r];
        }
    }
    #undef STAGE_KV
}

// ---------------- launcher ------------------------------------------------
extern "C" void kernel_launch(void* const* d_in, const int* in_sizes, int n_in,
                              void* d_out, int out_size, void* d_ws, size_t ws_size,
                              hipStream_t stream) {
    const float* x  = (const float*)d_in[0];
    const float* Wq = (const float*)d_in[1];
    const float* bq = (const float*)d_in[2];
    const float* Wk = (const float*)d_in[3];
    const float* bk = (const float*)d_in[4];
    const float* Wv = (const float*)d_in[5];
    const float* bv = (const float*)d_in[6];
    float* out = (float*)d_out;

    u16* Qf = (u16*)d_ws;                            // 8 MB (fragment layout)
    u16* Kf = Qf + (size_t)NROW * D_DIM;             // 8 MB
    u16* Vf = Kf + (size_t)NROW * D_DIM;             // 8 MB
    float* LZ = (float*)(Vf + (size_t)NROW * D_DIM); // 64 KB
    u16* Wf = (u16*)(LZ + NROW);                     // 384 KB

    wconv<<<96, 256, 0, stream>>>(Wq, Wk, Wv, Wf);
    qkv_proj<<<NROW / 32, 256, 0, stream>>>(x, Wf, bq, bk, bv, Qf, Kf, Vf);
    col_denom<<<256, 256, 0, stream>>>(Qf, Kf, LZ);
    attn_out<<<256, 256, 0, stream>>>(Qf, Kf, Vf, LZ, out);
}